// Round 4
// baseline (4932.149 us; speedup 1.0000x reference)
//
#include <hip/hip_runtime.h>
#include <hip/hip_bf16.h>

typedef __attribute__((ext_vector_type(8))) short short8;
typedef __attribute__((ext_vector_type(4))) float f32x4;
typedef __hip_bfloat16 bf16_t;

#define BATCH 4096
#define ISZ 64
#define HSZ 256
#define TSZ 64

// split a double into 3 bf16 planes (repr error ~2^-26 relative)
__device__ __forceinline__ void split3(double x, bf16_t& p0, bf16_t& p1, bf16_t& p2) {
  p0 = __float2bfloat16((float)x);
  double r1 = x - (double)__bfloat162float(p0);
  p1 = __float2bfloat16((float)r1);
  double r2 = r1 - (double)__bfloat162float(p1);
  p2 = __float2bfloat16((float)r2);
}

// ---------------- spectral norm prep, fp64 (1 block) ----------------
__global__ __launch_bounds__(256) void prep_sn(
    const float* __restrict__ w_lin, const float* __restrict__ u_sn,
    double* __restrict__ w_sn_f64)
{
  __shared__ double v[HSZ];
  __shared__ double red[256];
  __shared__ double Wv[ISZ];
  int t = threadIdx.x;
  // v = l2norm(W^T u)
  double s = 0.0;
  for (int i = 0; i < ISZ; ++i) s += (double)w_lin[i * HSZ + t] * (double)u_sn[i];
  red[t] = s * s;
  __syncthreads();
  for (int off = 128; off > 0; off >>= 1) { if (t < off) red[t] += red[t + off]; __syncthreads(); }
  double nv = sqrt(red[0]);
  v[t] = s / (nv + 1e-12);
  __syncthreads();
  // Wv = W v
  {
    int i = t >> 2, p = t & 3;
    double ps = 0.0;
    for (int k = p * 64; k < p * 64 + 64; ++k) ps += (double)w_lin[i * HSZ + k] * v[k];
    red[t] = ps;
    __syncthreads();
    if ((t & 3) == 0) Wv[i] = red[t] + red[t + 1] + red[t + 2] + red[t + 3];
    __syncthreads();
  }
  red[t] = (t < ISZ) ? Wv[t] * Wv[t] : 0.0;
  __syncthreads();
  for (int off = 128; off > 0; off >>= 1) { if (t < off) red[t] += red[t + off]; __syncthreads(); }
  double nw = sqrt(red[0]);
  double sigma = red[0] / (nw + 1e-12);  // u.(Wv), u = Wv/(|Wv|+eps)
  double inv_sigma = 1.0 / sigma;
  for (int idx = t; idx < ISZ * HSZ; idx += 256)
    w_sn_f64[idx] = (double)w_lin[idx] * inv_sigma;
}

// ---------------- elementwise split casts (layout-preserving) ----------------
__global__ __launch_bounds__(256) void split_cast_f32(
    const float* __restrict__ x, bf16_t* __restrict__ p0, bf16_t* __restrict__ p1,
    bf16_t* __restrict__ p2, int n)
{
  int i = blockIdx.x * 256 + threadIdx.x;
  if (i < n) {
    bf16_t a, b, c;
    split3((double)x[i], a, b, c);
    p0[i] = a; p1[i] = b; p2[i] = c;
  }
}

__global__ __launch_bounds__(256) void split_cast_f64(
    const double* __restrict__ x, bf16_t* __restrict__ p0, bf16_t* __restrict__ p1,
    bf16_t* __restrict__ p2, int n)
{
  int i = blockIdx.x * 256 + threadIdx.x;
  if (i < n) {
    bf16_t a, b, c;
    split3(x[i], a, b, c);
    p0[i] = a; p1[i] = b; p2[i] = c;
  }
}

// ---------------- step kernel 1: gi + gh + cell ----------------
// Mirrors reference: gi = x @ w_ih.T + b_ih (K=64), gh = h @ w_hh.T + b_hh (K=256),
// r=sig(i_r+h_r), z=sig(i_z+h_z), n=tanh(i_n + r*h_n), h' = (1-z)n + z h.
// Weights in NATURAL layout: w_ih [768,64], w_hh [768,256], row c = g*256 + j.
// Grid (BATCH/128, 16); block 256 = 4 waves; wave = 32 rows x (16 j x {rSum,zSum,iN,hN}).
// Split-precision: accM = plane0*plane0 main chain; accC = order-1/2 corrections.
template <bool FIRST>
__global__ __launch_bounds__(256) void gru_gates(
    const bf16_t* __restrict__ X0, const bf16_t* __restrict__ X1, const bf16_t* __restrict__ X2,
    const bf16_t* __restrict__ H0, const bf16_t* __restrict__ H1, const bf16_t* __restrict__ H2,
    const bf16_t* __restrict__ Wi0, const bf16_t* __restrict__ Wi1, const bf16_t* __restrict__ Wi2,
    const bf16_t* __restrict__ Wh0, const bf16_t* __restrict__ Wh1, const bf16_t* __restrict__ Wh2,
    const float* __restrict__ b_ih, const float* __restrict__ b_hh,
    const double* __restrict__ h64_in, double* __restrict__ h64_out,
    bf16_t* __restrict__ O0, bf16_t* __restrict__ O1, bf16_t* __restrict__ O2)
{
  const int jb = blockIdx.y;
  const int mw = blockIdx.x * 128 + (threadIdx.x >> 6) * 32;
  const int l = threadIdx.x & 63;
  const int lr = l & 15;
  const int lq = l >> 4;
  const int j = jb * 16 + lr;

  f32x4 accM[2][4], accC[2][4];
#pragma unroll
  for (int mt = 0; mt < 2; ++mt)
#pragma unroll
    for (int g = 0; g < 4; ++g) {
      accM[mt][g] = (f32x4){0.f, 0.f, 0.f, 0.f};
      accC[mt][g] = (f32x4){0.f, 0.f, 0.f, 0.f};
    }

  // ---- gi: x @ w_ih.T  (K = 64); gates g=0,1,2 -> acc cols 0,1,2
#pragma unroll
  for (int kk = 0; kk < ISZ; kk += 32) {
    short8 a0[2], a1[2], a2[2];
#pragma unroll
    for (int mt = 0; mt < 2; ++mt) {
      size_t ao = (size_t)(mw + mt * 16 + lr) * ISZ + kk + lq * 8;
      a0[mt] = *reinterpret_cast<const short8*>(X0 + ao);
      a1[mt] = *reinterpret_cast<const short8*>(X1 + ao);
      a2[mt] = *reinterpret_cast<const short8*>(X2 + ao);
    }
#pragma unroll
    for (int g = 0; g < 3; ++g) {
      size_t bo = (size_t)(g * HSZ + jb * 16 + lr) * ISZ + kk + lq * 8;
      short8 b0 = *reinterpret_cast<const short8*>(Wi0 + bo);
      short8 b1 = *reinterpret_cast<const short8*>(Wi1 + bo);
      short8 b2 = *reinterpret_cast<const short8*>(Wi2 + bo);
#pragma unroll
      for (int mt = 0; mt < 2; ++mt) {
        accC[mt][g] = __builtin_amdgcn_mfma_f32_16x16x32_bf16(a0[mt], b2, accC[mt][g], 0, 0, 0);
        accC[mt][g] = __builtin_amdgcn_mfma_f32_16x16x32_bf16(a1[mt], b1, accC[mt][g], 0, 0, 0);
        accC[mt][g] = __builtin_amdgcn_mfma_f32_16x16x32_bf16(a2[mt], b0, accC[mt][g], 0, 0, 0);
        accC[mt][g] = __builtin_amdgcn_mfma_f32_16x16x32_bf16(a0[mt], b1, accC[mt][g], 0, 0, 0);
        accC[mt][g] = __builtin_amdgcn_mfma_f32_16x16x32_bf16(a1[mt], b0, accC[mt][g], 0, 0, 0);
        accM[mt][g] = __builtin_amdgcn_mfma_f32_16x16x32_bf16(a0[mt], b0, accM[mt][g], 0, 0, 0);
      }
    }
  }

  // ---- gh: h @ w_hh.T (K = 256); gates g=0,1 -> acc cols 0,1 (sum with gi); g=2 -> col 3
  if (!FIRST) {
    for (int kk = 0; kk < HSZ; kk += 32) {
      short8 a0[2], a1[2], a2[2];
#pragma unroll
      for (int mt = 0; mt < 2; ++mt) {
        size_t ao = (size_t)(mw + mt * 16 + lr) * HSZ + kk + lq * 8;
        a0[mt] = *reinterpret_cast<const short8*>(H0 + ao);
        a1[mt] = *reinterpret_cast<const short8*>(H1 + ao);
        a2[mt] = *reinterpret_cast<const short8*>(H2 + ao);
      }
#pragma unroll
      for (int g = 0; g < 3; ++g) {
        const int tgt = (g == 2) ? 3 : g;
        size_t bo = (size_t)(g * HSZ + jb * 16 + lr) * HSZ + kk + lq * 8;
        short8 b0 = *reinterpret_cast<const short8*>(Wh0 + bo);
        short8 b1 = *reinterpret_cast<const short8*>(Wh1 + bo);
        short8 b2 = *reinterpret_cast<const short8*>(Wh2 + bo);
#pragma unroll
        for (int mt = 0; mt < 2; ++mt) {
          accC[mt][tgt] = __builtin_amdgcn_mfma_f32_16x16x32_bf16(a0[mt], b2, accC[mt][tgt], 0, 0, 0);
          accC[mt][tgt] = __builtin_amdgcn_mfma_f32_16x16x32_bf16(a1[mt], b1, accC[mt][tgt], 0, 0, 0);
          accC[mt][tgt] = __builtin_amdgcn_mfma_f32_16x16x32_bf16(a2[mt], b0, accC[mt][tgt], 0, 0, 0);
          accC[mt][tgt] = __builtin_amdgcn_mfma_f32_16x16x32_bf16(a0[mt], b1, accC[mt][tgt], 0, 0, 0);
          accC[mt][tgt] = __builtin_amdgcn_mfma_f32_16x16x32_bf16(a1[mt], b0, accC[mt][tgt], 0, 0, 0);
          accM[mt][tgt] = __builtin_amdgcn_mfma_f32_16x16x32_bf16(a0[mt], b0, accM[mt][tgt], 0, 0, 0);
        }
      }
    }
  }

  const double bir = (double)b_ih[0 * HSZ + j];
  const double biz = (double)b_ih[1 * HSZ + j];
  const double bin = (double)b_ih[2 * HSZ + j];
  const double bhr = (double)b_hh[0 * HSZ + j];
  const double bhz = (double)b_hh[1 * HSZ + j];
  const double bhn = (double)b_hh[2 * HSZ + j];

#pragma unroll
  for (int mt = 0; mt < 2; ++mt) {
#pragma unroll
    for (int q = 0; q < 4; ++q) {
      int b = mw + mt * 16 + lq * 4 + q;  // C/D: row=(lane>>4)*4+reg, col=lane&15
      double rpre = (double)accM[mt][0][q] + (double)accC[mt][0][q] + bir + bhr;
      double zpre = (double)accM[mt][1][q] + (double)accC[mt][1][q] + biz + bhz;
      double inn  = (double)accM[mt][2][q] + (double)accC[mt][2][q] + bin;
      double hnn  = (double)accM[mt][3][q] + (double)accC[mt][3][q] + bhn;
      double r = 1.0 / (1.0 + exp(-rpre));
      double z = 1.0 / (1.0 + exp(-zpre));
      double n = tanh(inn + r * hnn);
      size_t idx = (size_t)b * HSZ + j;
      double hold = FIRST ? 0.0 : h64_in[idx];
      double hv = (1.0 - z) * n + z * hold;
      h64_out[idx] = hv;
      bf16_t p0, p1, p2;
      split3(hv, p0, p1, p2);
      O0[idx] = p0; O1[idx] = p1; O2[idx] = p2;
    }
  }
}

// ---------------- step kernel 2: y = h @ w_sn.T + b_lin; emit y (output) and x-planes ----------------
// Grid BATCH/128; block 256 = 4 waves; wave = 32 rows x 64 cols.
__global__ __launch_bounds__(256) void y_step(
    const bf16_t* __restrict__ H0, const bf16_t* __restrict__ H1, const bf16_t* __restrict__ H2,
    const bf16_t* __restrict__ Ws0, const bf16_t* __restrict__ Ws1, const bf16_t* __restrict__ Ws2,
    const float* __restrict__ b_lin,
    float* __restrict__ yout,          // [BATCH, 64] slice of d_out
    bf16_t* __restrict__ X0, bf16_t* __restrict__ X1, bf16_t* __restrict__ X2)
{
  const int mw = blockIdx.x * 128 + (threadIdx.x >> 6) * 32;
  const int l = threadIdx.x & 63;
  const int lr = l & 15;
  const int lq = l >> 4;

  f32x4 accM[2][4], accC[2][4];
#pragma unroll
  for (int mt = 0; mt < 2; ++mt)
#pragma unroll
    for (int nt = 0; nt < 4; ++nt) {
      accM[mt][nt] = (f32x4){0.f, 0.f, 0.f, 0.f};
      accC[mt][nt] = (f32x4){0.f, 0.f, 0.f, 0.f};
    }

  for (int kk = 0; kk < HSZ; kk += 32) {
    short8 a0[2], a1[2], a2[2];
#pragma unroll
    for (int mt = 0; mt < 2; ++mt) {
      size_t ao = (size_t)(mw + mt * 16 + lr) * HSZ + kk + lq * 8;
      a0[mt] = *reinterpret_cast<const short8*>(H0 + ao);
      a1[mt] = *reinterpret_cast<const short8*>(H1 + ao);
      a2[mt] = *reinterpret_cast<const short8*>(H2 + ao);
    }
#pragma unroll
    for (int nt = 0; nt < 4; ++nt) {
      size_t bo = (size_t)(nt * 16 + lr) * HSZ + kk + lq * 8;
      short8 b0 = *reinterpret_cast<const short8*>(Ws0 + bo);
      short8 b1 = *reinterpret_cast<const short8*>(Ws1 + bo);
      short8 b2 = *reinterpret_cast<const short8*>(Ws2 + bo);
#pragma unroll
      for (int mt = 0; mt < 2; ++mt) {
        accC[mt][nt] = __builtin_amdgcn_mfma_f32_16x16x32_bf16(a0[mt], b2, accC[mt][nt], 0, 0, 0);
        accC[mt][nt] = __builtin_amdgcn_mfma_f32_16x16x32_bf16(a1[mt], b1, accC[mt][nt], 0, 0, 0);
        accC[mt][nt] = __builtin_amdgcn_mfma_f32_16x16x32_bf16(a2[mt], b0, accC[mt][nt], 0, 0, 0);
        accC[mt][nt] = __builtin_amdgcn_mfma_f32_16x16x32_bf16(a0[mt], b1, accC[mt][nt], 0, 0, 0);
        accC[mt][nt] = __builtin_amdgcn_mfma_f32_16x16x32_bf16(a1[mt], b0, accC[mt][nt], 0, 0, 0);
        accM[mt][nt] = __builtin_amdgcn_mfma_f32_16x16x32_bf16(a0[mt], b0, accM[mt][nt], 0, 0, 0);
      }
    }
  }

#pragma unroll
  for (int mt = 0; mt < 2; ++mt)
#pragma unroll
    for (int q = 0; q < 4; ++q) {
      size_t row = mw + mt * 16 + lq * 4 + q;
#pragma unroll
      for (int nt = 0; nt < 4; ++nt) {
        int o = nt * 16 + lr;
        double y = (double)accM[mt][nt][q] + (double)accC[mt][nt][q] + (double)b_lin[o];
        float yf = (float)y;
        size_t oi = row * 64 + o;
        yout[oi] = yf;
        bf16_t p0, p1, p2;
        split3((double)yf, p0, p1, p2);  // feed back the fp32-rounded y, like the reference
        X0[oi] = p0; X1[oi] = p1; X2[oi] = p2;
      }
    }
}

// ---------------- BatchNorm (fp64 stats) ----------------
__global__ __launch_bounds__(256) void bn_stats(const float* __restrict__ Y,
                                                float* __restrict__ mean,
                                                float* __restrict__ istd)
{
  int t = blockIdx.x;
  int o = threadIdx.x & 63, bg = threadIdx.x >> 6;
  const float* Yt = Y + (size_t)t * BATCH * 64;
  double s = 0.0, s2 = 0.0;
  for (int b = bg; b < BATCH; b += 4) {
    double v = (double)Yt[(size_t)b * 64 + o];
    s += v;
    s2 += v * v;
  }
  __shared__ double ls[4][64], ls2[4][64];
  ls[bg][o] = s;
  ls2[bg][o] = s2;
  __syncthreads();
  if (bg == 0) {
    s = ls[0][o] + ls[1][o] + ls[2][o] + ls[3][o];
    s2 = ls2[0][o] + ls2[1][o] + ls2[2][o] + ls2[3][o];
    double m = s * (1.0 / BATCH);
    double var = s2 * (1.0 / BATCH) - m * m;
    mean[t * 64 + o] = (float)m;
    istd[t * 64 + o] = (float)(1.0 / sqrt(var + 1e-5));
  }
}

__global__ __launch_bounds__(256) void bn_norm(float* __restrict__ Y,
                                               const float* __restrict__ mean,
                                               const float* __restrict__ istd, int n4)
{
  for (int i = blockIdx.x * 256 + threadIdx.x; i < n4; i += gridDim.x * 256) {
    f32x4 v = reinterpret_cast<f32x4*>(Y)[i];
    int base = i * 4;
    int o = base & 63;
    int t = base >> 18;  // / (BATCH*64)
    const float* mr = mean + t * 64;
    const float* ir = istd + t * 64;
#pragma unroll
    for (int e = 0; e < 4; ++e) v[e] = (v[e] - mr[o + e]) * ir[o + e];
    reinterpret_cast<f32x4*>(Y)[i] = v;
  }
}

extern "C" void kernel_launch(void* const* d_in, const int* in_sizes, int n_in,
                              void* d_out, int out_size, void* d_ws, size_t ws_size,
                              hipStream_t stream)
{
  const float* inputs = (const float*)d_in[0];
  const float* w_ih = (const float*)d_in[1];
  const float* w_hh = (const float*)d_in[2];
  const float* b_ih = (const float*)d_in[3];
  const float* b_hh = (const float*)d_in[4];
  const float* w_lin = (const float*)d_in[5];
  const float* b_lin = (const float*)d_in[6];
  const float* u_sn = (const float*)d_in[7];
  float* out = (float*)d_out;

  const size_t BH = (size_t)BATCH * HSZ;
  const size_t BI = (size_t)BATCH * ISZ;

  char* ws = (char*)d_ws;
  size_t off = 0;
  auto alloc = [&](size_t bytes) -> void* {
    void* p = ws + off;
    off += (bytes + 255) & ~(size_t)255;
    return p;
  };
  double* w_sn_f64 = (double*)alloc((size_t)ISZ * HSZ * 8);
  bf16_t* Wi0 = (bf16_t*)alloc((size_t)3 * HSZ * ISZ * 2);
  bf16_t* Wi1 = (bf16_t*)alloc((size_t)3 * HSZ * ISZ * 2);
  bf16_t* Wi2 = (bf16_t*)alloc((size_t)3 * HSZ * ISZ * 2);
  bf16_t* Wh0 = (bf16_t*)alloc((size_t)3 * HSZ * HSZ * 2);
  bf16_t* Wh1 = (bf16_t*)alloc((size_t)3 * HSZ * HSZ * 2);
  bf16_t* Wh2 = (bf16_t*)alloc((size_t)3 * HSZ * HSZ * 2);
  bf16_t* Ws0 = (bf16_t*)alloc((size_t)ISZ * HSZ * 2);
  bf16_t* Ws1 = (bf16_t*)alloc((size_t)ISZ * HSZ * 2);
  bf16_t* Ws2 = (bf16_t*)alloc((size_t)ISZ * HSZ * 2);
  bf16_t* X0 = (bf16_t*)alloc(BI * 2);
  bf16_t* X1 = (bf16_t*)alloc(BI * 2);
  bf16_t* X2 = (bf16_t*)alloc(BI * 2);
  bf16_t* HA0 = (bf16_t*)alloc(BH * 2);
  bf16_t* HA1 = (bf16_t*)alloc(BH * 2);
  bf16_t* HA2 = (bf16_t*)alloc(BH * 2);
  bf16_t* HB0 = (bf16_t*)alloc(BH * 2);
  bf16_t* HB1 = (bf16_t*)alloc(BH * 2);
  bf16_t* HB2 = (bf16_t*)alloc(BH * 2);
  double* h64A = (double*)alloc(BH * 8);
  double* h64B = (double*)alloc(BH * 8);
  float* meanb = (float*)alloc(TSZ * 64 * 4);
  float* istdb = (float*)alloc(TSZ * 64 * 4);
  if (off > ws_size) return;

  prep_sn<<<1, 256, 0, stream>>>(w_lin, u_sn, w_sn_f64);
  split_cast_f32<<<(3 * HSZ * ISZ + 255) / 256, 256, 0, stream>>>(w_ih, Wi0, Wi1, Wi2, 3 * HSZ * ISZ);
  split_cast_f32<<<(3 * HSZ * HSZ + 255) / 256, 256, 0, stream>>>(w_hh, Wh0, Wh1, Wh2, 3 * HSZ * HSZ);
  split_cast_f64<<<(ISZ * HSZ + 255) / 256, 256, 0, stream>>>(w_sn_f64, Ws0, Ws1, Ws2, ISZ * HSZ);
  split_cast_f32<<<((int)BI + 255) / 256, 256, 0, stream>>>(inputs, X0, X1, X2, (int)BI);

  bf16_t *Hin0 = HB0, *Hin1 = HB1, *Hin2 = HB2;
  bf16_t *Hout0 = HA0, *Hout1 = HA1, *Hout2 = HA2;
  double* hin = h64B;
  double* hout = h64A;
  const dim3 g1(BATCH / 128, 16);

  for (int t = 0; t < TSZ; ++t) {
    if (t == 0) {
      gru_gates<true><<<g1, 256, 0, stream>>>(
          X0, X1, X2, nullptr, nullptr, nullptr,
          Wi0, Wi1, Wi2, Wh0, Wh1, Wh2, b_ih, b_hh,
          nullptr, hout, Hout0, Hout1, Hout2);
    } else {
      gru_gates<false><<<g1, 256, 0, stream>>>(
          X0, X1, X2, Hin0, Hin1, Hin2,
          Wi0, Wi1, Wi2, Wh0, Wh1, Wh2, b_ih, b_hh,
          hin, hout, Hout0, Hout1, Hout2);
    }
    y_step<<<BATCH / 128, 256, 0, stream>>>(
        Hout0, Hout1, Hout2, Ws0, Ws1, Ws2, b_lin,
        out + (size_t)t * BATCH * 64, X0, X1, X2);
    // swap ping-pong
    { bf16_t* tm;
      tm = Hin0; Hin0 = Hout0; Hout0 = tm;
      tm = Hin1; Hin1 = Hout1; Hout1 = tm;
      tm = Hin2; Hin2 = Hout2; Hout2 = tm; }
    { double* tm = hin; hin = hout; hout = tm; }
  }

  bn_stats<<<TSZ, 256, 0, stream>>>(out, meanb, istdb);
  bn_norm<<<2048, 256, 0, stream>>>(out, meanb, istdb, TSZ * BATCH * 64 / 4);
}

// Round 5
// 2342.667 us; speedup vs baseline: 2.1054x; 2.1054x over previous
//
#include <hip/hip_runtime.h>
#include <hip/hip_bf16.h>

typedef __attribute__((ext_vector_type(8))) short short8;
typedef __attribute__((ext_vector_type(4))) float f32x4;
typedef __hip_bfloat16 bf16_t;

#define BATCH 4096
#define ISZ 64
#define HSZ 256
#define TSZ 64

__device__ __forceinline__ float sigm(float x) { return 1.f / (1.f + __expf(-x)); }
__device__ __forceinline__ float tanh_fast(float x) { return 1.f - 2.f / (1.f + __expf(2.f * x)); }

// split a double into 3 bf16 planes (repr error ~2^-26 relative)
__device__ __forceinline__ void split3(double x, bf16_t& p0, bf16_t& p1, bf16_t& p2) {
  p0 = __float2bfloat16((float)x);
  double r1 = x - (double)__bfloat162float(p0);
  p1 = __float2bfloat16((float)r1);
  double r2 = r1 - (double)__bfloat162float(p1);
  p2 = __float2bfloat16((float)r2);
}

// ---------------- spectral norm prep, fp64 (1 block) ----------------
__global__ __launch_bounds__(256) void prep_sn(
    const float* __restrict__ w_lin, const float* __restrict__ u_sn,
    double* __restrict__ w_sn_f64)
{
  __shared__ double v[HSZ];
  __shared__ double red[256];
  __shared__ double Wv[ISZ];
  int t = threadIdx.x;
  double s = 0.0;
  for (int i = 0; i < ISZ; ++i) s += (double)w_lin[i * HSZ + t] * (double)u_sn[i];
  red[t] = s * s;
  __syncthreads();
  for (int off = 128; off > 0; off >>= 1) { if (t < off) red[t] += red[t + off]; __syncthreads(); }
  double nv = sqrt(red[0]);
  v[t] = s / (nv + 1e-12);
  __syncthreads();
  {
    int i = t >> 2, p = t & 3;
    double ps = 0.0;
    for (int k = p * 64; k < p * 64 + 64; ++k) ps += (double)w_lin[i * HSZ + k] * v[k];
    red[t] = ps;
    __syncthreads();
    if ((t & 3) == 0) Wv[i] = red[t] + red[t + 1] + red[t + 2] + red[t + 3];
    __syncthreads();
  }
  red[t] = (t < ISZ) ? Wv[t] * Wv[t] : 0.0;
  __syncthreads();
  for (int off = 128; off > 0; off >>= 1) { if (t < off) red[t] += red[t + off]; __syncthreads(); }
  double nw = sqrt(red[0]);
  double sigma = red[0] / (nw + 1e-12);  // u.(Wv), u = Wv/(|Wv|+eps)
  double inv_sigma = 1.0 / sigma;
  for (int idx = t; idx < ISZ * HSZ; idx += 256)
    w_sn_f64[idx] = (double)w_lin[idx] * inv_sigma;
}

// ---------------- 2-plane split casts (layout-preserving) ----------------
__global__ __launch_bounds__(256) void split2_f32(
    const float* __restrict__ x, bf16_t* __restrict__ p0, bf16_t* __restrict__ p1, int n)
{
  int i = blockIdx.x * 256 + threadIdx.x;
  if (i < n) {
    float v = x[i];
    bf16_t a = __float2bfloat16(v);
    p0[i] = a;
    p1[i] = __float2bfloat16(v - __bfloat162float(a));
  }
}

__global__ __launch_bounds__(256) void split2_f64(
    const double* __restrict__ x, bf16_t* __restrict__ p0, bf16_t* __restrict__ p1, int n)
{
  int i = blockIdx.x * 256 + threadIdx.x;
  if (i < n) {
    double v = x[i];
    bf16_t a = __float2bfloat16((float)v);
    p0[i] = a;
    p1[i] = __float2bfloat16((float)(v - (double)__bfloat162float(a)));
  }
}

// ---------------- step kernel 1: gi + gh + cell ----------------
// gi = x @ w_ih.T + b_ih (K=64), gh = h @ w_hh.T + b_hh (K=256), fused GRU cell.
// 2-plane split GEMM: X*W ~= x0w0 (accM) + x0w1 + x1w0 (accC). Operand err 2^-17.5.
// H state carried as 3 bf16 planes (2^-26); plane 2 used only for the z*h_old term.
// Grid (BATCH/128, 16); block 256 = 4 waves; wave = 32 rows x 16 j x {rSum,zSum,iN,hN}.
template <bool FIRST>
__global__ __launch_bounds__(256) void gru_gates(
    const bf16_t* __restrict__ X0, const bf16_t* __restrict__ X1,
    const bf16_t* __restrict__ H0, const bf16_t* __restrict__ H1, const bf16_t* __restrict__ H2,
    const bf16_t* __restrict__ Wi0, const bf16_t* __restrict__ Wi1,
    const bf16_t* __restrict__ Wh0, const bf16_t* __restrict__ Wh1,
    const float* __restrict__ b_ih, const float* __restrict__ b_hh,
    bf16_t* __restrict__ O0, bf16_t* __restrict__ O1, bf16_t* __restrict__ O2)
{
  const int jb = blockIdx.y;
  const int mw = blockIdx.x * 128 + (threadIdx.x >> 6) * 32;
  const int l = threadIdx.x & 63;
  const int lr = l & 15;
  const int lq = l >> 4;
  const int j = jb * 16 + lr;

  f32x4 accM[2][4], accC[2][4];
#pragma unroll
  for (int mt = 0; mt < 2; ++mt)
#pragma unroll
    for (int g = 0; g < 4; ++g) {
      accM[mt][g] = (f32x4){0.f, 0.f, 0.f, 0.f};
      accC[mt][g] = (f32x4){0.f, 0.f, 0.f, 0.f};
    }

  // ---- gi: x @ w_ih.T (K=64); gates 0,1,2 -> acc cols 0,1,2
#pragma unroll
  for (int kk = 0; kk < ISZ; kk += 32) {
    short8 a0[2], a1[2];
#pragma unroll
    for (int mt = 0; mt < 2; ++mt) {
      size_t ao = (size_t)(mw + mt * 16 + lr) * ISZ + kk + lq * 8;
      a0[mt] = *reinterpret_cast<const short8*>(X0 + ao);
      a1[mt] = *reinterpret_cast<const short8*>(X1 + ao);
    }
#pragma unroll
    for (int g = 0; g < 3; ++g) {
      size_t bo = (size_t)(g * HSZ + jb * 16 + lr) * ISZ + kk + lq * 8;
      short8 b0 = *reinterpret_cast<const short8*>(Wi0 + bo);
      short8 b1 = *reinterpret_cast<const short8*>(Wi1 + bo);
#pragma unroll
      for (int mt = 0; mt < 2; ++mt) {
        accC[mt][g] = __builtin_amdgcn_mfma_f32_16x16x32_bf16(a0[mt], b1, accC[mt][g], 0, 0, 0);
        accC[mt][g] = __builtin_amdgcn_mfma_f32_16x16x32_bf16(a1[mt], b0, accC[mt][g], 0, 0, 0);
        accM[mt][g] = __builtin_amdgcn_mfma_f32_16x16x32_bf16(a0[mt], b0, accM[mt][g], 0, 0, 0);
      }
    }
  }

  // ---- gh: h @ w_hh.T (K=256); gates 0,1 -> cols 0,1 (summed with gi); gate 2 -> col 3
  if (!FIRST) {
    for (int kk = 0; kk < HSZ; kk += 32) {
      short8 a0[2], a1[2];
#pragma unroll
      for (int mt = 0; mt < 2; ++mt) {
        size_t ao = (size_t)(mw + mt * 16 + lr) * HSZ + kk + lq * 8;
        a0[mt] = *reinterpret_cast<const short8*>(H0 + ao);
        a1[mt] = *reinterpret_cast<const short8*>(H1 + ao);
      }
#pragma unroll
      for (int g = 0; g < 3; ++g) {
        const int tgt = (g == 2) ? 3 : g;
        size_t bo = (size_t)(g * HSZ + jb * 16 + lr) * HSZ + kk + lq * 8;
        short8 b0 = *reinterpret_cast<const short8*>(Wh0 + bo);
        short8 b1 = *reinterpret_cast<const short8*>(Wh1 + bo);
#pragma unroll
        for (int mt = 0; mt < 2; ++mt) {
          accC[mt][tgt] = __builtin_amdgcn_mfma_f32_16x16x32_bf16(a0[mt], b1, accC[mt][tgt], 0, 0, 0);
          accC[mt][tgt] = __builtin_amdgcn_mfma_f32_16x16x32_bf16(a1[mt], b0, accC[mt][tgt], 0, 0, 0);
          accM[mt][tgt] = __builtin_amdgcn_mfma_f32_16x16x32_bf16(a0[mt], b0, accM[mt][tgt], 0, 0, 0);
        }
      }
    }
  }

  const float brz = b_ih[0 * HSZ + j] + b_hh[0 * HSZ + j];
  const float bzz = b_ih[1 * HSZ + j] + b_hh[1 * HSZ + j];
  const float bin = b_ih[2 * HSZ + j];
  const float bhn = b_hh[2 * HSZ + j];

#pragma unroll
  for (int mt = 0; mt < 2; ++mt) {
#pragma unroll
    for (int q = 0; q < 4; ++q) {
      int b = mw + mt * 16 + lq * 4 + q;  // C/D: row=(lane>>4)*4+reg, col=lane&15
      float rpre = accM[mt][0][q] + accC[mt][0][q] + brz;
      float zpre = accM[mt][1][q] + accC[mt][1][q] + bzz;
      float inn  = accM[mt][2][q] + accC[mt][2][q] + bin;
      float hnn  = accM[mt][3][q] + accC[mt][3][q] + bhn;
      float r = sigm(rpre);
      float z = sigm(zpre);
      float n = tanh_fast(inn + r * hnn);
      size_t idx = (size_t)b * HSZ + j;
      double hold = 0.0;
      if (!FIRST)
        hold = (double)__bfloat162float(H0[idx]) + (double)__bfloat162float(H1[idx]) +
               (double)__bfloat162float(H2[idx]);
      double hv = (double)((1.f - z) * n) + (double)z * hold;
      bf16_t p0, p1, p2;
      split3(hv, p0, p1, p2);
      O0[idx] = p0; O1[idx] = p1; O2[idx] = p2;
    }
  }
}

// ---------------- step kernel 2: y = h @ w_sn.T + b_lin; emit y and next-x planes ----------------
// Grid BATCH/16 one-wave blocks; wave = 16 rows x 64 cols (4 col tiles).
__global__ __launch_bounds__(64) void y_step(
    const bf16_t* __restrict__ H0, const bf16_t* __restrict__ H1,
    const bf16_t* __restrict__ Ws0, const bf16_t* __restrict__ Ws1,
    const float* __restrict__ b_lin,
    float* __restrict__ yout,          // [BATCH, 64] slice of d_out
    bf16_t* __restrict__ X0, bf16_t* __restrict__ X1)
{
  const int mw = blockIdx.x * 16;
  const int l = threadIdx.x;
  const int lr = l & 15;
  const int lq = l >> 4;

  f32x4 accM[4], accC[4];
#pragma unroll
  for (int nt = 0; nt < 4; ++nt) {
    accM[nt] = (f32x4){0.f, 0.f, 0.f, 0.f};
    accC[nt] = (f32x4){0.f, 0.f, 0.f, 0.f};
  }

  for (int kk = 0; kk < HSZ; kk += 32) {
    size_t ao = (size_t)(mw + lr) * HSZ + kk + lq * 8;
    short8 a0 = *reinterpret_cast<const short8*>(H0 + ao);
    short8 a1 = *reinterpret_cast<const short8*>(H1 + ao);
#pragma unroll
    for (int nt = 0; nt < 4; ++nt) {
      size_t bo = (size_t)(nt * 16 + lr) * HSZ + kk + lq * 8;
      short8 b0 = *reinterpret_cast<const short8*>(Ws0 + bo);
      short8 b1 = *reinterpret_cast<const short8*>(Ws1 + bo);
      accC[nt] = __builtin_amdgcn_mfma_f32_16x16x32_bf16(a0, b1, accC[nt], 0, 0, 0);
      accC[nt] = __builtin_amdgcn_mfma_f32_16x16x32_bf16(a1, b0, accC[nt], 0, 0, 0);
      accM[nt] = __builtin_amdgcn_mfma_f32_16x16x32_bf16(a0, b0, accM[nt], 0, 0, 0);
    }
  }

#pragma unroll
  for (int q = 0; q < 4; ++q) {
    size_t row = mw + lq * 4 + q;
#pragma unroll
    for (int nt = 0; nt < 4; ++nt) {
      int o = nt * 16 + lr;
      float yf = accM[nt][q] + accC[nt][q] + b_lin[o];
      size_t oi = row * 64 + o;
      yout[oi] = yf;
      bf16_t p0 = __float2bfloat16(yf);
      X0[oi] = p0;
      X1[oi] = __float2bfloat16(yf - __bfloat162float(p0));
    }
  }
}

// ---------------- BatchNorm: two-stage stats + normalize ----------------
// Stage 1: grid (TSZ, 16); each block reduces 256 rows -> partial[t][chunk][o]
__global__ __launch_bounds__(256) void bn_part(const float* __restrict__ Y,
                                               double* __restrict__ psum,
                                               double* __restrict__ psum2)
{
  int t = blockIdx.x;
  int chunk = blockIdx.y;
  int o = threadIdx.x & 63, rg = threadIdx.x >> 6;
  const float* Yt = Y + (size_t)t * BATCH * 64;
  int b0 = chunk * 256;
  double s = 0.0, s2 = 0.0;
  for (int b = b0 + rg; b < b0 + 256; b += 4) {
    double v = (double)Yt[(size_t)b * 64 + o];
    s += v;
    s2 += v * v;
  }
  __shared__ double ls[4][64], ls2[4][64];
  ls[rg][o] = s;
  ls2[rg][o] = s2;
  __syncthreads();
  if (rg == 0) {
    s = ls[0][o] + ls[1][o] + ls[2][o] + ls[3][o];
    s2 = ls2[0][o] + ls2[1][o] + ls2[2][o] + ls2[3][o];
    size_t pi = ((size_t)t * 16 + chunk) * 64 + o;
    psum[pi] = s;
    psum2[pi] = s2;
  }
}

__global__ __launch_bounds__(64) void bn_final(const double* __restrict__ psum,
                                               const double* __restrict__ psum2,
                                               float* __restrict__ mean,
                                               float* __restrict__ istd)
{
  int t = blockIdx.x;
  int o = threadIdx.x;
  double s = 0.0, s2 = 0.0;
  for (int c = 0; c < 16; ++c) {
    size_t pi = ((size_t)t * 16 + c) * 64 + o;
    s += psum[pi];
    s2 += psum2[pi];
  }
  double m = s * (1.0 / BATCH);
  double var = s2 * (1.0 / BATCH) - m * m;
  mean[t * 64 + o] = (float)m;
  istd[t * 64 + o] = (float)(1.0 / sqrt(var + 1e-5));
}

__global__ __launch_bounds__(256) void bn_norm(float* __restrict__ Y,
                                               const float* __restrict__ mean,
                                               const float* __restrict__ istd, int n4)
{
  for (int i = blockIdx.x * 256 + threadIdx.x; i < n4; i += gridDim.x * 256) {
    f32x4 v = reinterpret_cast<f32x4*>(Y)[i];
    int base = i * 4;
    int o = base & 63;
    int t = base >> 18;  // / (BATCH*64)
    const float* mr = mean + t * 64;
    const float* ir = istd + t * 64;
#pragma unroll
    for (int e = 0; e < 4; ++e) v[e] = (v[e] - mr[o + e]) * ir[o + e];
    reinterpret_cast<f32x4*>(Y)[i] = v;
  }
}

extern "C" void kernel_launch(void* const* d_in, const int* in_sizes, int n_in,
                              void* d_out, int out_size, void* d_ws, size_t ws_size,
                              hipStream_t stream)
{
  const float* inputs = (const float*)d_in[0];
  const float* w_ih = (const float*)d_in[1];
  const float* w_hh = (const float*)d_in[2];
  const float* b_ih = (const float*)d_in[3];
  const float* b_hh = (const float*)d_in[4];
  const float* w_lin = (const float*)d_in[5];
  const float* b_lin = (const float*)d_in[6];
  const float* u_sn = (const float*)d_in[7];
  float* out = (float*)d_out;

  const size_t BH = (size_t)BATCH * HSZ;
  const size_t BI = (size_t)BATCH * ISZ;

  char* ws = (char*)d_ws;
  size_t off = 0;
  auto alloc = [&](size_t bytes) -> void* {
    void* p = ws + off;
    off += (bytes + 255) & ~(size_t)255;
    return p;
  };
  double* w_sn_f64 = (double*)alloc((size_t)ISZ * HSZ * 8);
  bf16_t* Wi0 = (bf16_t*)alloc((size_t)3 * HSZ * ISZ * 2);
  bf16_t* Wi1 = (bf16_t*)alloc((size_t)3 * HSZ * ISZ * 2);
  bf16_t* Wh0 = (bf16_t*)alloc((size_t)3 * HSZ * HSZ * 2);
  bf16_t* Wh1 = (bf16_t*)alloc((size_t)3 * HSZ * HSZ * 2);
  bf16_t* Ws0 = (bf16_t*)alloc((size_t)ISZ * HSZ * 2);
  bf16_t* Ws1 = (bf16_t*)alloc((size_t)ISZ * HSZ * 2);
  bf16_t* X0 = (bf16_t*)alloc(BI * 2);
  bf16_t* X1 = (bf16_t*)alloc(BI * 2);
  bf16_t* HA0 = (bf16_t*)alloc(BH * 2);
  bf16_t* HA1 = (bf16_t*)alloc(BH * 2);
  bf16_t* HA2 = (bf16_t*)alloc(BH * 2);
  bf16_t* HB0 = (bf16_t*)alloc(BH * 2);
  bf16_t* HB1 = (bf16_t*)alloc(BH * 2);
  bf16_t* HB2 = (bf16_t*)alloc(BH * 2);
  double* psum = (double*)alloc((size_t)TSZ * 16 * 64 * 8);
  double* psum2 = (double*)alloc((size_t)TSZ * 16 * 64 * 8);
  float* meanb = (float*)alloc(TSZ * 64 * 4);
  float* istdb = (float*)alloc(TSZ * 64 * 4);
  if (off > ws_size) return;

  prep_sn<<<1, 256, 0, stream>>>(w_lin, u_sn, w_sn_f64);
  split2_f32<<<(3 * HSZ * ISZ + 255) / 256, 256, 0, stream>>>(w_ih, Wi0, Wi1, 3 * HSZ * ISZ);
  split2_f32<<<(3 * HSZ * HSZ + 255) / 256, 256, 0, stream>>>(w_hh, Wh0, Wh1, 3 * HSZ * HSZ);
  split2_f64<<<(ISZ * HSZ + 255) / 256, 256, 0, stream>>>(w_sn_f64, Ws0, Ws1, ISZ * HSZ);
  split2_f32<<<((int)BI + 255) / 256, 256, 0, stream>>>(inputs, X0, X1, (int)BI);

  bf16_t *Hin0 = HB0, *Hin1 = HB1, *Hin2 = HB2;
  bf16_t *Hout0 = HA0, *Hout1 = HA1, *Hout2 = HA2;
  const dim3 g1(BATCH / 128, 16);

  for (int t = 0; t < TSZ; ++t) {
    if (t == 0) {
      gru_gates<true><<<g1, 256, 0, stream>>>(
          X0, X1, nullptr, nullptr, nullptr,
          Wi0, Wi1, Wh0, Wh1, b_ih, b_hh, Hout0, Hout1, Hout2);
    } else {
      gru_gates<false><<<g1, 256, 0, stream>>>(
          X0, X1, Hin0, Hin1, Hin2,
          Wi0, Wi1, Wh0, Wh1, b_ih, b_hh, Hout0, Hout1, Hout2);
    }
    y_step<<<BATCH / 16, 64, 0, stream>>>(
        Hout0, Hout1, Ws0, Ws1, b_lin,
        out + (size_t)t * BATCH * 64, X0, X1);
    { bf16_t* tm;
      tm = Hin0; Hin0 = Hout0; Hout0 = tm;
      tm = Hin1; Hin1 = Hout1; Hout1 = tm;
      tm = Hin2; Hin2 = Hout2; Hout2 = tm; }
  }

  bn_part<<<dim3(TSZ, 16), 256, 0, stream>>>(out, psum, psum2);
  bn_final<<<TSZ, 64, 0, stream>>>(psum, psum2, meanb, istdb);
  bn_norm<<<2048, 256, 0, stream>>>(out, meanb, istdb, TSZ * BATCH * 64 / 4);
}